// Round 3
// baseline (238.225 us; speedup 1.0000x reference)
//
#include <hip/hip_runtime.h>

#define TT 2048
#define CC 1024

typedef __attribute__((ext_vector_type(8))) __bf16 bf16x8;
typedef __attribute__((ext_vector_type(4))) float f32x4;
typedef unsigned int u32;

__device__ __forceinline__ short f2bf(float f) {
  u32 u = __float_as_uint(f);
  u += 0x7fffu + ((u >> 16) & 1u);  // RTNE
  return (short)(u >> 16);
}

#if __has_builtin(__builtin_amdgcn_cvt_pk_bf16_f32)
__device__ __forceinline__ u32 pack2(float a, float b) {
  auto v = __builtin_amdgcn_cvt_pk_bf16_f32(a, b);
  return __builtin_bit_cast(u32, v);
}
#else
__device__ __forceinline__ u32 pack2(float a, float b) {
  u32 ua = __float_as_uint(a), ub = __float_as_uint(b);
  ua += 0x7fffu + ((ua >> 16) & 1u);
  ub += 0x7fffu + ((ub >> 16) & 1u);
  return (ua >> 16) | (ub & 0xffff0000u);
}
#endif

// ---------------- fused fp32 -> bf16 cast (x | wqkv(Q scaled) | wout) ---------
__global__ __launch_bounds__(256) void cvt_all(const float* __restrict__ x,
                                               const float* __restrict__ wqkv,
                                               const float* __restrict__ wout,
                                               short* __restrict__ dst) {
  int i = blockIdx.x * blockDim.x + threadIdx.x;  // float4 index, < 3145728
  const float* src;
  float sc = 1.0f;
  if (i < 2097152) {
    src = x + (size_t)i * 4;
  } else if (i < 2883584) {
    int j = i - 2097152;
    src = wqkv + (size_t)j * 4;
    if (j < 262144) sc = 0.125f;  // Q block: fold attention scale (exact pow2)
  } else {
    src = wout + (size_t)(i - 2883584) * 4;
  }
  float4 f = *reinterpret_cast<const float4*>(src);
  short4 s;
  s.x = f2bf(f.x * sc); s.y = f2bf(f.y * sc); s.z = f2bf(f.z * sc); s.w = f2bf(f.w * sc);
  reinterpret_cast<short4*>(dst)[i] = s;
}

__device__ __forceinline__ void storev(float* p, float v) { *p = v; }
__device__ __forceinline__ void storev(short* p, float v) { *p = f2bf(v); }

#if __has_builtin(__builtin_amdgcn_global_load_lds)
#define HAVE_GLD_LDS 1
__device__ __forceinline__ void gld_lds16(const short* g, short* l) {
  __builtin_amdgcn_global_load_lds((const __attribute__((address_space(1))) u32*)g,
                                   (__attribute__((address_space(3))) u32*)l, 16, 0, 0);
}
#endif

__device__ __forceinline__ f32x4 mfma16(bf16x8 a, bf16x8 b, f32x4 c) {
  return __builtin_amdgcn_mfma_f32_16x16x32_bf16(a, b, c, 0, 0, 0);
}

template <int NN>
__device__ __forceinline__ void waitvm() {
  if constexpr (NN == 0) asm volatile("s_waitcnt vmcnt(0)" ::: "memory");
  else if constexpr (NN == 4) asm volatile("s_waitcnt vmcnt(4)" ::: "memory");
  else if constexpr (NN == 6) asm volatile("s_waitcnt vmcnt(6)" ::: "memory");
  else if constexpr (NN == 8) asm volatile("s_waitcnt vmcnt(8)" ::: "memory");
}

template <int MH, int NFR>
__device__ __forceinline__ void mmaN(f32x4 (&acc)[8][NFR], const bf16x8 (&af)[4],
                                     const bf16x8 (&bfr)[NFR]) {
#pragma unroll
  for (int mf = 0; mf < 4; ++mf)
#pragma unroll
    for (int nf = 0; nf < NFR; ++nf)
      acc[MH * 4 + mf][nf] = mfma16(af[mf], bfr[nf], acc[MH * 4 + mf][nf]);
}

// =================== C[M,N] = A[M,K] * B[N,K]^T, 256xBN 8-phase ===============
// 512 thr = 8 waves (2M x 4N), BK=64. LDS: 2 dbuf x {A[256][64], B[BN][64]}
// split in two k-panels of [rows][32] shorts (64B rows). k-slot XOR swizzle
// (slot ^= (row>>1)&3) via pre-swizzled GLOBAL source + linear global_load_lds
// dest; ds_read_b128 lands 2 dwords/bank/quarter-wave = conflict-free.
// Per-wave stage sizes: A-half = 2 glds, B-half = BGLD = BN/128 glds.
// Schedule (8 phases per iteration = 2 K-tiles; tile t -> buf[t&1]):
//   P1 rd(b0,ks0,mh0)+B   stage A(b1,ks1,2i+1)
//   P2 rd(b0,ks0,mh1)     stage B(b0,ks0,2i+2)
//   P3 rd(b0,ks1,mh0)+B   stage A(b0,ks0,2i+2)
//   P4 rd(b0,ks1,mh1)     stage B(b0,ks1,2i+2)   vmcnt(2+2*BGLD)
//   P5 rd(b1,ks0,mh0)+B   stage A(b0,ks1,2i+2)
//   P6 rd(b1,ks0,mh1)     stage B(b1,ks0,2i+3)
//   P7 rd(b1,ks1,mh0)+B   stage A(b1,ks0,2i+3)
//   P8 rd(b1,ks1,mh1)     stage B(b1,ks1,2i+3)   vmcnt(2+2*BGLD)
// ONE barrier per phase (overlapped form): ds_read issue + stage issue, then
// MFMAs with COMPILER-counted lgkmcnt waits (LDS pipe overlaps matrix pipe),
// then lgkmcnt(0) [cross-wave WAR: all reads of this phase drained before any
// wave's next-phase stage can issue past the barrier], optional vmcnt, barrier.
// Counting/WAR audit: every stage target's readers are >=1 phase earlier and
// drained by that phase's trailing lgkmcnt(0)+barrier; reads of phase p can
// hoist at most past the previous barrier to after phase p-1's waitcnt asms
// ("memory" clobbers bound all motion), where their staged data has already
// been vmcnt-drained. In-wave VMEM issue order is preserved -> vmcnt(N) math
// unchanged; never drains to 0 in the main loop.
#define GPHASE(DB, KS, MH, LOADB, STG, SYNC)               \
  {                                                        \
    ldA(af, DB, KS, MH);                                   \
    if (LOADB) ldB(bfr, DB, KS);                           \
    STG;                                                   \
    __builtin_amdgcn_s_setprio(1);                         \
    mmaN<MH>(acc, af, bfr);                                \
    __builtin_amdgcn_s_setprio(0);                         \
    asm volatile("s_waitcnt lgkmcnt(0)" ::: "memory");     \
    SYNC;                                                  \
    __builtin_amdgcn_s_barrier();                          \
  }
#define GNOOP ((void)0)

// Grid: 1D, TM*TN tiles (TM = M/256 = 32, TN = N/BN). XCD-chunked swizzle:
// xcd = id%8 owns a contiguous 8m x RN tile region (requires TN == 2*RN).
template <typename OutT, int N, int K, int BN, int RN>
__global__ __launch_bounds__(512, 2) void gemm8p(const short* __restrict__ A,
                                                 const short* __restrict__ B,
                                                 OutT* __restrict__ Cm) {
  constexpr int BGLD = BN / 128;        // glds per B-half stage per wave
  constexpr int NFR = BN / 64;          // B frags per wave
  constexpr int SYNCN = 2 + 2 * BGLD;   // steady-state vmcnt
  constexpr int NT = K / 64, NITER = NT / 2;
  constexpr int BHALF = BN * 32;        // shorts per B half-panel
  constexpr int DBS = 16384 + BN * 64;  // shorts per dbuf half (A pair + B pair)
  extern __shared__ short lds[];
  const int tid = threadIdx.x;
  const int wave = tid >> 6, lane = tid & 63;
  const int quad = lane >> 4, nl = lane & 15;
  const int wm = wave >> 2, wn = wave & 3;

  const int id = blockIdx.x;
  const int xcd = id & 7, slot = id >> 3;
  const int mt = (xcd & 3) * 8 + (slot & 7);
  const int nt = (xcd >> 2) * RN + (slot >> 3);
  const int m0 = mt * 256, n0 = nt * BN;

  // stage source: wave owns 32 A-rows / BN/8 B-rows; lane -> (row = L>>2, slot
  // permuted (L&3)^((L>>3)&3)); permutation stays inside 64B segs (coalesced).
  const int srow = lane >> 2;
  const int sperm = ((lane & 3) ^ ((lane >> 3) & 3)) * 8;
  const short* pA = A + (size_t)(m0 + wave * 32 + srow) * K + sperm;
  const short* pB = B + (size_t)(n0 + wave * (BN / 8) + srow) * K + sperm;

  // frag read: LDS(row, slot_lin) holds global slot (slot_lin ^ ((row>>1)&3))
  const int perm = (quad ^ ((nl >> 1) & 3)) * 8;
  const int aoff = (wm * 128 + nl) * 32 + perm;
  const int boff = (wn * (BN / 4) + nl) * 32 + perm;

  f32x4 acc[8][NFR] = {};

  auto stageA = [&](int db, int ks, int t) {
    const short* s = pA + (size_t)t * 64 + ks * 32;
    short* d = lds + db * DBS + ks * 8192 + wave * 1024;
#if HAVE_GLD_LDS
    gld_lds16(s, d);
    gld_lds16(s + (size_t)16 * K, d + 512);
#else
    *reinterpret_cast<uint4*>(d + lane * 8) = *reinterpret_cast<const uint4*>(s);
    *reinterpret_cast<uint4*>(d + 512 + lane * 8) =
        *reinterpret_cast<const uint4*>(s + (size_t)16 * K);
#endif
  };
  auto stageB = [&](int db, int ks, int t) {
    const short* s = pB + (size_t)t * 64 + ks * 32;
    short* d = lds + db * DBS + 16384 + ks * BHALF + wave * (BN * 4);
#if HAVE_GLD_LDS
    gld_lds16(s, d);
    if constexpr (BGLD == 2) gld_lds16(s + (size_t)16 * K, d + 512);
#else
    *reinterpret_cast<uint4*>(d + lane * 8) = *reinterpret_cast<const uint4*>(s);
    if constexpr (BGLD == 2)
      *reinterpret_cast<uint4*>(d + 512 + lane * 8) =
          *reinterpret_cast<const uint4*>(s + (size_t)16 * K);
#endif
  };
  auto ldA = [&](bf16x8 (&af)[4], int db, int ks, int mh) {
#pragma unroll
    for (int mf = 0; mf < 4; ++mf)
      af[mf] = *reinterpret_cast<const bf16x8*>(
          &lds[db * DBS + ks * 8192 + aoff + (mh * 4 + mf) * 512]);
  };
  auto ldB = [&](bf16x8 (&bfr)[NFR], int db, int ks) {
#pragma unroll
    for (int nf = 0; nf < NFR; ++nf)
      bfr[nf] = *reinterpret_cast<const bf16x8*>(
          &lds[db * DBS + 16384 + ks * BHALF + boff + nf * 512]);
  };

  // prologue: tile0 fully + tile1 {B_klo, A_klo, B_khi} (A_khi comes at P1).
  // After tile0's last stage (B01), later issues = B10+A10+B11 = SYNCN.
  stageA(0, 0, 0); stageA(0, 1, 0); stageB(0, 0, 0); stageB(0, 1, 0);
  stageB(1, 0, 1); stageA(1, 0, 1); stageB(1, 1, 1);
  waitvm<SYNCN>();
  __builtin_amdgcn_s_barrier();

  for (int i = 0; i < NITER - 1; ++i) {
    const int to1 = 2 * i + 1, te2 = 2 * i + 2, to3 = 2 * i + 3;
    bf16x8 af[4], bfr[NFR];
    GPHASE(0, 0, 0, 1, stageA(1, 1, to1), GNOOP)
    GPHASE(0, 0, 1, 0, stageB(0, 0, te2), GNOOP)
    GPHASE(0, 1, 0, 1, stageA(0, 0, te2), GNOOP)
    GPHASE(0, 1, 1, 0, stageB(0, 1, te2), waitvm<SYNCN>())
    GPHASE(1, 0, 0, 1, stageA(0, 1, te2), GNOOP)
    GPHASE(1, 0, 1, 0, stageB(1, 0, to3), GNOOP)
    GPHASE(1, 1, 0, 1, stageA(1, 0, to3), GNOOP)
    GPHASE(1, 1, 1, 0, stageB(1, 1, to3), waitvm<SYNCN>())
  }
  {  // last iteration: only tile NT-1's A_khi still needs staging
    bf16x8 af[4], bfr[NFR];
    GPHASE(0, 0, 0, 1, stageA(1, 1, NT - 1), GNOOP)
    GPHASE(0, 0, 1, 0, GNOOP, GNOOP)
    GPHASE(0, 1, 0, 1, GNOOP, GNOOP)
    GPHASE(0, 1, 1, 0, GNOOP, waitvm<0>())
    GPHASE(1, 0, 0, 1, GNOOP, GNOOP)
    GPHASE(1, 0, 1, 0, GNOOP, GNOOP)
    GPHASE(1, 1, 0, 1, GNOOP, GNOOP)
    GPHASE(1, 1, 1, 0, GNOOP, GNOOP)
  }

#pragma unroll
  for (int mf = 0; mf < 8; ++mf) {
    const int row = m0 + wm * 128 + mf * 16 + quad * 4;
#pragma unroll
    for (int nf = 0; nf < NFR; ++nf) {
      const int col = n0 + wn * (BN / 4) + nf * 16 + nl;
#pragma unroll
      for (int r = 0; r < 4; ++r)
        storev(&Cm[(size_t)(row + r) * N + col], acc[mf][nf][r]);
    }
  }
}

// ---------------- V transpose: qkv V-part -> Vt[bh][d][t] ---------------------
__global__ __launch_bounds__(256) void transpose_v(const short* __restrict__ qkv,
                                                   short* __restrict__ vt) {
  __shared__ short Ls[64 * 68];
  const int bh = blockIdx.y, tb = blockIdx.x;
  const int b = bh >> 4, h = bh & 15;
  const int tid = threadIdx.x;
  const short* src = qkv + (size_t)(b * TT + tb * 64) * (3 * CC) + 2 * CC + h * 64;
#pragma unroll
  for (int i = 0; i < 2; ++i) {
    int idx = tid + i * 256;
    int tl = idx >> 3, dc = idx & 7;
    uint4 d4 = *reinterpret_cast<const uint4*>(&src[(size_t)tl * (3 * CC) + dc * 8]);
    *reinterpret_cast<uint2*>(&Ls[tl * 68 + dc * 8]) = make_uint2(d4.x, d4.y);
    *reinterpret_cast<uint2*>(&Ls[tl * 68 + dc * 8 + 4]) = make_uint2(d4.z, d4.w);
  }
  __syncthreads();
  short* dst = vt + (size_t)(bh * 64) * TT + tb * 64;
#pragma unroll
  for (int i = 0; i < 2; ++i) {
    int idx = tid + i * 256;
    int dl = idx >> 3, tc = idx & 7;
    short tmp[8];
#pragma unroll
    for (int j = 0; j < 8; ++j) tmp[j] = Ls[(tc * 8 + j) * 68 + dl];
    *reinterpret_cast<uint4*>(&dst[(size_t)dl * TT + tc * 8]) = *reinterpret_cast<uint4*>(tmp);
  }
}

// ---------------- attention compute (one 32-col half-chunk, one wave) ---------
template <bool DIAG>
__device__ __forceinline__ void attn_compute(const short* kf, const short* vf, u32* ssw,
                                             const bf16x8 (&qf)[2][2], f32x4 (&o)[2][4],
                                             int lane, int quad, int nl) {
  bf16x8 k00 = *reinterpret_cast<const bf16x8*>(&kf[0 * 512 + lane * 8]);
  bf16x8 k01 = *reinterpret_cast<const bf16x8*>(&kf[1 * 512 + lane * 8]);
  bf16x8 k10 = *reinterpret_cast<const bf16x8*>(&kf[2 * 512 + lane * 8]);
  bf16x8 k11 = *reinterpret_cast<const bf16x8*>(&kf[3 * 512 + lane * 8]);
  bf16x8 vB[4];
#pragma unroll
  for (int nb = 0; nb < 4; ++nb)
    vB[nb] = *reinterpret_cast<const bf16x8*>(&vf[nb * 512 + lane * 8]);
  {
    u32* srow = &ssw[0 * 320 + nl * 20];
    f32x4 s0 = {};
    s0 = mfma16(k00, qf[0][0], s0);
    s0 = mfma16(k01, qf[0][1], s0);
    if (DIAG) {
#pragma unroll
      for (int r = 0; r < 4; ++r) s0[r] = (quad * 4 + r <= nl) ? s0[r] : 0.0f;
    }
#pragma unroll
    for (int p = 0; p < 2; ++p) srow[quad * 2 + p] = pack2(s0[2 * p], s0[2 * p + 1]);
    if (DIAG) {
#pragma unroll
      for (int p = 0; p < 2; ++p) srow[8 + quad * 2 + p] = 0;
    } else {
      f32x4 s1 = {};
      s1 = mfma16(k10, qf[0][0], s1);
      s1 = mfma16(k11, qf[0][1], s1);
#pragma unroll
      for (int p = 0; p < 2; ++p) srow[8 + quad * 2 + p] = pack2(s1[2 * p], s1[2 * p + 1]);
    }
  }
  {
    u32* srow = &ssw[1 * 320 + nl * 20];
    f32x4 s0 = {}, s1 = {};
    s0 = mfma16(k00, qf[1][0], s0);
    s0 = mfma16(k01, qf[1][1], s0);
    s1 = mfma16(k10, qf[1][0], s1);
    s1 = mfma16(k11, qf[1][1], s1);
    if (DIAG) {
#pragma unroll
      for (int r = 0; r < 4; ++r) s1[r] = (quad * 4 + r <= nl) ? s1[r] : 0.0f;
    }
#pragma unroll
    for (int p = 0; p < 2; ++p) {
      srow[quad * 2 + p] = pack2(s0[2 * p], s0[2 * p + 1]);
      srow[8 + quad * 2 + p] = pack2(s1[2 * p], s1[2 * p + 1]);
    }
  }
#pragma unroll
  for (int m = 0; m < 2; ++m) {
    bf16x8 sf = *reinterpret_cast<const bf16x8*>(&ssw[m * 320 + nl * 20 + quad * 4]);
#pragma unroll
    for (int nb = 0; nb < 4; ++nb) o[m][nb] = mfma16(sf, vB[nb], o[m][nb]);
  }
}

// ---------------- causal masked attention (no softmax) ------------------------
__global__ __launch_bounds__(256, 3) void attn_kernel(const short* __restrict__ qkv,
                                                      const short* __restrict__ vt,
                                                      short* __restrict__ attnb) {
  const int bh = blockIdx.x;
  const int b = bh >> 4, h = bh & 15;
  const int ti = 15 - blockIdx.y;  // big tiles first
  const int T0 = ti * 128;
  const int tid = threadIdx.x;
  const int wave = tid >> 6, lane = tid & 63;
  const int quad = lane >> 4, nl = lane & 15;

  const short* qbase = qkv + (size_t)(b * TT) * (3 * CC) + h * 64;
  const short* kbase = qbase + CC;
  const short* vbase = vt + (size_t)(bh * 64) * TT;

  __shared__ __align__(16) short Frag[2][8192];  // 2 x 16 KB staged K/V frags
  __shared__ __align__(16) u32 Ss[4][640];       // per-wave S roundtrip (stride 20)
  u32* ssw = Ss[wave];

  const int tw0 = T0 + wave * 32;
  bf16x8 qf[2][2];  // Q B-frags (pre-scaled by 0.125)
#pragma unroll
  for (int m = 0; m < 2; ++m)
#pragma unroll
    for (int half = 0; half < 2; ++half)
      qf[m][half] = *reinterpret_cast<const bf16x8*>(
          &qbase[(size_t)(tw0 + m * 16 + nl) * (3 * CC) + half * 32 + quad * 8]);

  f32x4 o[2][4] = {};

  const short* ksrc = kbase + (size_t)(wave * 16 + nl) * (3 * CC) + quad * 8;
  const int sp_w = wave >> 1, nb0 = (wave & 1) * 2;
  const short* vsrc0 = vbase + (size_t)((nb0 + 0) * 16 + nl) * TT + sp_w * 32 + quad * 8;
  const short* vsrc1 = vbase + (size_t)((nb0 + 1) * 16 + nl) * TT + sp_w * 32 + quad * 8;

  auto stage = [&](short* fb, int c) {
    const size_t koff = (size_t)(c * 64) * (3 * CC);
#if HAVE_GLD_LDS
    gld_lds16(ksrc + koff, &fb[(2 * wave) * 512]);
    gld_lds16(ksrc + koff + 32, &fb[(2 * wave + 1) * 512]);
    gld_lds16(vsrc0 + c * 64, &fb[4096 + (2 * wave) * 512]);
    gld_lds16(vsrc1 + c * 64, &fb[4096 + (2 * wave + 1) * 512]);
#else
    *reinterpret_cast<uint4*>(&fb[(2 * wave) * 512 + lane * 8]) =
        *reinterpret_cast<const uint4*>(ksrc + koff);
    *reinterpret_cast<uint4*>(&fb[(2 * wave + 1) * 512 + lane * 8]) =
        *reinterpret_cast<const uint4*>(ksrc + koff + 32);
    *reinterpret_cast<uint4*>(&fb[4096 + (2 * wave) * 512 + lane * 8]) =
        *reinterpret_cast<const uint4*>(vsrc0 + c * 64);
    *reinterpret_cast<uint4*>(&fb[4096 + (2 * wave + 1) * 512 + lane * 8]) =
        *reinterpret_cast<const uint4*>(vsrc1 + c * 64);
#endif
  };

  const int nch = 2 * ti + 2;     // 64-col chunks
  const int cd = 4 * ti + wave;   // this wave's diagonal 32-chunk index

  stage(Frag[0], 0);
  for (int c = 0; c < nch; ++c) {
    __syncthreads();  // compiler vmcnt(0) here drains stage(c); buf[c&1] ready
    if (c + 1 < nch) stage(Frag[(c + 1) & 1], c + 1);  // overlaps compute below
    const short* fb = Frag[c & 1];
    const int c0 = 2 * c, c1 = 2 * c + 1;
    if (c0 < cd)
      attn_compute<false>(fb, fb + 4096, ssw, qf, o, lane, quad, nl);
    else if (c0 == cd)
      attn_compute<true>(fb, fb + 4096, ssw, qf, o, lane, quad, nl);
    if (c1 < cd)
      attn_compute<false>(fb + 2048, fb + 4096 + 2048, ssw, qf, o, lane, quad, nl);
    else if (c1 == cd)
      attn_compute<true>(fb + 2048, fb + 4096 + 2048, ssw, qf, o, lane, quad, nl);
  }

#pragma unroll
  for (int m = 0; m < 2; ++m)
#pragma unroll
    for (int nb = 0; nb < 4; ++nb)
#pragma unroll
      for (int r = 0; r < 4; ++r) {
        int t = tw0 + m * 16 + quad * 4 + r;
        attnb[(size_t)(b * TT + t) * CC + h * 64 + nb * 16 + nl] = f2bf(o[m][nb][r]);
      }
}

extern "C" void kernel_launch(void* const* d_in, const int* in_sizes, int n_in,
                              void* d_out, int out_size, void* d_ws, size_t ws_size,
                              hipStream_t stream) {
  const float* x = (const float*)d_in[0];      // [4,2048,1024]
  const float* wqkv = (const float*)d_in[1];   // [3072,1024]
  const float* wout = (const float*)d_in[2];   // [1024,1024]
  float* out = (float*)d_out;                  // [4,2048,1024] fp32

  char* ws = (char*)d_ws;
  short* xb    = (short*)(ws);                  // 16.78 MB
  short* wqkvb = (short*)(ws + 16777216);       //  6.29 MB
  short* woutb = (short*)(ws + 23068672);       //  2.10 MB
  short* qkvb  = (short*)(ws + 25165824);       // 50.33 MB
  short* attnb = (short*)(ws + 75497472);       // 16.78 MB  (total 92.27 MB)
  short* vt    = xb;  // xb dead after QKV GEMM

  static bool inited = false;
  if (!inited) {  // dynamic LDS opt-in (not a stream op; capture-safe)
    hipFuncSetAttribute(reinterpret_cast<const void*>(&gemm8p<short, 3072, 1024, 256, 6>),
                        hipFuncAttributeMaxDynamicSharedMemorySize, 131072);
    hipFuncSetAttribute(reinterpret_cast<const void*>(&gemm8p<float, 1024, 1024, 128, 4>),
                        hipFuncAttributeMaxDynamicSharedMemorySize, 98304);
    inited = true;
  }

  cvt_all<<<12288, 256, 0, stream>>>(x, wqkv, wout, xb);

  // QKV: M=8192, N=3072, BN=256 -> 32x12 = 384 tiles (1.5 rounds)
  gemm8p<short, 3072, 1024, 256, 6><<<384, 512, 131072, stream>>>(xb, wqkvb, qkvb);

  transpose_v<<<dim3(32, 64), 256, 0, stream>>>(qkvb, vt);

  attn_kernel<<<dim3(64, 16), 256, 0, stream>>>(qkvb, vt, attnb);

  // out-proj: M=8192, N=1024, BN=128 -> 32x8 = 256 tiles (1 exact round)
  gemm8p<float, 1024, 1024, 128, 4><<<256, 512, 98304, stream>>>(attnb, woutb, out);
}

// Round 4
// 231.974 us; speedup vs baseline: 1.0269x; 1.0269x over previous
//
#include <hip/hip_runtime.h>

#define TT 2048
#define CC 1024

typedef __attribute__((ext_vector_type(8))) __bf16 bf16x8;
typedef __attribute__((ext_vector_type(4))) float f32x4;
typedef unsigned int u32;

__device__ __forceinline__ short f2bf(float f) {
  u32 u = __float_as_uint(f);
  u += 0x7fffu + ((u >> 16) & 1u);  // RTNE
  return (short)(u >> 16);
}

#if __has_builtin(__builtin_amdgcn_cvt_pk_bf16_f32)
__device__ __forceinline__ u32 pack2(float a, float b) {
  auto v = __builtin_amdgcn_cvt_pk_bf16_f32(a, b);
  return __builtin_bit_cast(u32, v);
}
#else
__device__ __forceinline__ u32 pack2(float a, float b) {
  u32 ua = __float_as_uint(a), ub = __float_as_uint(b);
  ua += 0x7fffu + ((ua >> 16) & 1u);
  ub += 0x7fffu + ((ub >> 16) & 1u);
  return (ua >> 16) | (ub & 0xffff0000u);
}
#endif

// ---------------- fused fp32 -> bf16 cast (x | wqkv(Q scaled) | wout) ---------
__global__ __launch_bounds__(256) void cvt_all(const float* __restrict__ x,
                                               const float* __restrict__ wqkv,
                                               const float* __restrict__ wout,
                                               short* __restrict__ dst) {
  int i = blockIdx.x * blockDim.x + threadIdx.x;  // float4 index, < 3145728
  const float* src;
  float sc = 1.0f;
  if (i < 2097152) {
    src = x + (size_t)i * 4;
  } else if (i < 2883584) {
    int j = i - 2097152;
    src = wqkv + (size_t)j * 4;
    if (j < 262144) sc = 0.125f;  // Q block: fold attention scale (exact pow2)
  } else {
    src = wout + (size_t)(i - 2883584) * 4;
  }
  float4 f = *reinterpret_cast<const float4*>(src);
  short4 s;
  s.x = f2bf(f.x * sc); s.y = f2bf(f.y * sc); s.z = f2bf(f.z * sc); s.w = f2bf(f.w * sc);
  reinterpret_cast<short4*>(dst)[i] = s;
}

__device__ __forceinline__ void storev(float* p, float v) { *p = v; }
__device__ __forceinline__ void storev(short* p, float v) { *p = f2bf(v); }

#if __has_builtin(__builtin_amdgcn_global_load_lds)
#define HAVE_GLD_LDS 1
__device__ __forceinline__ void gld_lds16(const short* g, short* l) {
  __builtin_amdgcn_global_load_lds((const __attribute__((address_space(1))) u32*)g,
                                   (__attribute__((address_space(3))) u32*)l, 16, 0, 0);
}
#endif

__device__ __forceinline__ f32x4 mfma16(bf16x8 a, bf16x8 b, f32x4 c) {
  return __builtin_amdgcn_mfma_f32_16x16x32_bf16(a, b, c, 0, 0, 0);
}

template <int NN>
__device__ __forceinline__ void waitvm() {
  if constexpr (NN == 0) asm volatile("s_waitcnt vmcnt(0)" ::: "memory");
  else if constexpr (NN == 3) asm volatile("s_waitcnt vmcnt(3)" ::: "memory");
  else if constexpr (NN == 4) asm volatile("s_waitcnt vmcnt(4)" ::: "memory");
  else if constexpr (NN == 6) asm volatile("s_waitcnt vmcnt(6)" ::: "memory");
  else if constexpr (NN == 8) asm volatile("s_waitcnt vmcnt(8)" ::: "memory");
}

// =================== C[M,N] = A[M,K] * B[N,K]^T, 128xBN 4-phase ===============
// 512 thr = 8 waves (2M x 4N), BK=64. LDS: 2 dbuf x {A[128][64], B[BN][64]}
// split in two k-panels of [rows][32] shorts (64B rows). k-slot XOR swizzle
// (slot ^= (row>>1)&3) via pre-swizzled GLOBAL source + linear global_load_lds
// dest; ds_read_b128 lands 2 dwords/bank/quarter-wave = conflict-free.
// Chunk c = (tile t = c>>1, ks = c&1); tile t -> buf t&1; 4 chunks of LDS slots.
// Phase(c) [one per chunk, 4 per iter = 2 K-tiles]:
//   { ldA(MFRAG) + ldB(NFR) ds_read_b128 of chunk c;
//     stage chunk c+3 (A: AGLD glds, B: BGLD glds; target slot = slot(c-1),
//       last read one phase ago, drained by that phase's lgkmcnt(0)+barrier);
//     setprio(1); MFRAG x NFR MFMA (compiler-counted lgkm waits); setprio(0);
//     lgkmcnt(0)  [cross-wave WAR for next phase's stage];
//     vmcnt(2*GPP) [forces chunk c+1 landed; chunks c+2, c+3 stay in flight —
//       never drains to 0 in the main loop];  s_barrier }
// Prologue stages chunks 0,1,2 then vmcnt(2*GPP) (chunk 0 landed). Tail phases
// stop staging and step the wait down 2*GPP -> GPP -> 0.
#define GNOOP ((void)0)
#define GPHASE4(DB, KS, STG, SYNC)                         \
  {                                                        \
    bf16x8 af[MFRAG], bfr[NFR];                            \
    ldA(af, DB, KS);                                       \
    ldB(bfr, DB, KS);                                      \
    STG;                                                   \
    __builtin_amdgcn_s_setprio(1);                         \
    mmaAll(af, bfr);                                       \
    __builtin_amdgcn_s_setprio(0);                         \
    asm volatile("s_waitcnt lgkmcnt(0)" ::: "memory");     \
    SYNC;                                                  \
    __builtin_amdgcn_s_barrier();                          \
  }

// Grid: 1D, TM*TN tiles (TM = M/128 = 64, TN = N/BN). XCD-chunked swizzle:
// xcd = id%8 owns mt in [xcd*8, xcd*8+8) x all nt (A-panel 2 MB L2-resident;
// consecutive slots share one B-panel).
template <typename OutT, int N, int K, int BM, int BN>
__global__ __launch_bounds__(512, 2) void gemm4p(const short* __restrict__ A,
                                                 const short* __restrict__ B,
                                                 OutT* __restrict__ Cm) {
  constexpr int MFRAG = BM / 32;       // A frags per wave (wave M = BM/2)
  constexpr int NFR = BN / 64;         // B frags per wave (wave N = BN/4)
  constexpr int AGLD = BM / 128;       // glds per A half-panel stage per wave
  constexpr int BGLD = BN / 128;       // glds per B half-panel stage per wave
  constexpr int GPP = AGLD + BGLD;     // glds per phase per wave
  constexpr int SYNCN = 2 * GPP;       // steady-state vmcnt
  constexpr int NT = K / 64, NITER = NT / 2;
  constexpr int DBS = 64 * (BM + BN);  // shorts per dbuf half
  constexpr int TMX = (8192 / BM) / 8; // m-tiles per XCD
  extern __shared__ short lds[];
  const int tid = threadIdx.x;
  const int wave = tid >> 6, lane = tid & 63;
  const int quad = lane >> 4, nl = lane & 15;
  const int wm = wave >> 2, wn = wave & 3;

  const int id = blockIdx.x;
  const int xcd = id & 7, slot = id >> 3;
  const int mt = xcd * TMX + (slot % TMX);
  const int nt = slot / TMX;
  const int m0 = mt * BM, n0 = nt * BN;

  // stage source: lane -> (row = lane>>2 within 16-row gld, slot permuted
  // (lane&3)^((lane>>3)&3)); permutation stays inside 64B segs (coalesced).
  const int srow = lane >> 2;
  const int sperm = ((lane & 3) ^ ((lane >> 3) & 3)) * 8;
  const short* pA = A + (size_t)(m0 + wave * (BM / 8) + srow) * K + sperm;
  const short* pB = B + (size_t)(n0 + wave * (BN / 8) + srow) * K + sperm;

  // frag read: LDS(row, slot_lin) holds global slot (slot_lin ^ ((row>>1)&3))
  const int perm = (quad ^ ((nl >> 1) & 3)) * 8;

  f32x4 acc[MFRAG][NFR] = {};

  auto stageA = [&](int db, int ks, int t) {
    const short* s = pA + (size_t)t * 64 + ks * 32;
    short* d = lds + db * DBS + ks * (BM * 32) + wave * (BM * 4);
#pragma unroll
    for (int j = 0; j < AGLD; ++j) {
#if HAVE_GLD_LDS
      gld_lds16(s + (size_t)j * 16 * K, d + j * 512);
#else
      *reinterpret_cast<uint4*>(d + j * 512 + lane * 8) =
          *reinterpret_cast<const uint4*>(s + (size_t)j * 16 * K);
#endif
    }
  };
  auto stageB = [&](int db, int ks, int t) {
    const short* s = pB + (size_t)t * 64 + ks * 32;
    short* d = lds + db * DBS + BM * 64 + ks * (BN * 32) + wave * (BN * 4);
#pragma unroll
    for (int j = 0; j < BGLD; ++j) {
#if HAVE_GLD_LDS
      gld_lds16(s + (size_t)j * 16 * K, d + j * 512);
#else
      *reinterpret_cast<uint4*>(d + j * 512 + lane * 8) =
          *reinterpret_cast<const uint4*>(s + (size_t)j * 16 * K);
#endif
    }
  };
  auto stage = [&](int db, int ks, int t) { stageA(db, ks, t); stageB(db, ks, t); };

  auto ldA = [&](bf16x8 (&af)[MFRAG], int db, int ks) {
#pragma unroll
    for (int mf = 0; mf < MFRAG; ++mf)
      af[mf] = *reinterpret_cast<const bf16x8*>(
          &lds[db * DBS + ks * (BM * 32) + (wm * (BM / 2) + mf * 16 + nl) * 32 + perm]);
  };
  auto ldB = [&](bf16x8 (&bfr)[NFR], int db, int ks) {
#pragma unroll
    for (int nf = 0; nf < NFR; ++nf)
      bfr[nf] = *reinterpret_cast<const bf16x8*>(
          &lds[db * DBS + BM * 64 + ks * (BN * 32) + (wn * (BN / 4) + nf * 16 + nl) * 32 + perm]);
  };
  auto mmaAll = [&](const bf16x8 (&af)[MFRAG], const bf16x8 (&bfr)[NFR]) {
#pragma unroll
    for (int mf = 0; mf < MFRAG; ++mf)
#pragma unroll
      for (int nf = 0; nf < NFR; ++nf)
        acc[mf][nf] = mfma16(af[mf], bfr[nf], acc[mf][nf]);
  };

  // prologue: chunks 0,1,2 (tile0 both halves + tile1 klo)
  stage(0, 0, 0); stage(0, 1, 0); stage(1, 0, 1);
  waitvm<SYNCN>();
  __builtin_amdgcn_s_barrier();

  for (int i = 0; i < NITER - 1; ++i) {
    GPHASE4(0, 0, stage(1, 1, 2 * i + 1), waitvm<SYNCN>())
    GPHASE4(0, 1, stage(0, 0, 2 * i + 2), waitvm<SYNCN>())
    GPHASE4(1, 0, stage(0, 1, 2 * i + 2), waitvm<SYNCN>())
    GPHASE4(1, 1, stage(1, 0, 2 * i + 3), waitvm<SYNCN>())
  }
  // tail iteration: last stage is chunk 2*NT-1; waits step down 2*GPP->GPP->0
  GPHASE4(0, 0, stage(1, 1, NT - 1), waitvm<SYNCN>())
  GPHASE4(0, 1, GNOOP, waitvm<GPP>())
  GPHASE4(1, 0, GNOOP, waitvm<0>())
  GPHASE4(1, 1, GNOOP, GNOOP)

#pragma unroll
  for (int mf = 0; mf < MFRAG; ++mf) {
    const int row = m0 + wm * (BM / 2) + mf * 16 + quad * 4;
#pragma unroll
    for (int nf = 0; nf < NFR; ++nf) {
      const int col = n0 + wn * (BN / 4) + nf * 16 + nl;
#pragma unroll
      for (int r = 0; r < 4; ++r)
        storev(&Cm[(size_t)(row + r) * N + col], acc[mf][nf][r]);
    }
  }
}

// ---------------- V transpose: qkv V-part -> Vt[bh][d][t] ---------------------
__global__ __launch_bounds__(256) void transpose_v(const short* __restrict__ qkv,
                                                   short* __restrict__ vt) {
  __shared__ short Ls[64 * 68];
  const int bh = blockIdx.y, tb = blockIdx.x;
  const int b = bh >> 4, h = bh & 15;
  const int tid = threadIdx.x;
  const short* src = qkv + (size_t)(b * TT + tb * 64) * (3 * CC) + 2 * CC + h * 64;
#pragma unroll
  for (int i = 0; i < 2; ++i) {
    int idx = tid + i * 256;
    int tl = idx >> 3, dc = idx & 7;
    uint4 d4 = *reinterpret_cast<const uint4*>(&src[(size_t)tl * (3 * CC) + dc * 8]);
    *reinterpret_cast<uint2*>(&Ls[tl * 68 + dc * 8]) = make_uint2(d4.x, d4.y);
    *reinterpret_cast<uint2*>(&Ls[tl * 68 + dc * 8 + 4]) = make_uint2(d4.z, d4.w);
  }
  __syncthreads();
  short* dst = vt + (size_t)(bh * 64) * TT + tb * 64;
#pragma unroll
  for (int i = 0; i < 2; ++i) {
    int idx = tid + i * 256;
    int dl = idx >> 3, tc = idx & 7;
    short tmp[8];
#pragma unroll
    for (int j = 0; j < 8; ++j) tmp[j] = Ls[(tc * 8 + j) * 68 + dl];
    *reinterpret_cast<uint4*>(&dst[(size_t)dl * TT + tc * 8]) = *reinterpret_cast<uint4*>(tmp);
  }
}

// ---------------- attention compute (one 32-col half-chunk, one wave) ---------
template <bool DIAG>
__device__ __forceinline__ void attn_compute(const short* kf, const short* vf, u32* ssw,
                                             const bf16x8 (&qf)[2][2], f32x4 (&o)[2][4],
                                             int lane, int quad, int nl) {
  bf16x8 k00 = *reinterpret_cast<const bf16x8*>(&kf[0 * 512 + lane * 8]);
  bf16x8 k01 = *reinterpret_cast<const bf16x8*>(&kf[1 * 512 + lane * 8]);
  bf16x8 k10 = *reinterpret_cast<const bf16x8*>(&kf[2 * 512 + lane * 8]);
  bf16x8 k11 = *reinterpret_cast<const bf16x8*>(&kf[3 * 512 + lane * 8]);
  bf16x8 vB[4];
#pragma unroll
  for (int nb = 0; nb < 4; ++nb)
    vB[nb] = *reinterpret_cast<const bf16x8*>(&vf[nb * 512 + lane * 8]);
  {
    u32* srow = &ssw[0 * 320 + nl * 20];
    f32x4 s0 = {};
    s0 = mfma16(k00, qf[0][0], s0);
    s0 = mfma16(k01, qf[0][1], s0);
    if (DIAG) {
#pragma unroll
      for (int r = 0; r < 4; ++r) s0[r] = (quad * 4 + r <= nl) ? s0[r] : 0.0f;
    }
#pragma unroll
    for (int p = 0; p < 2; ++p) srow[quad * 2 + p] = pack2(s0[2 * p], s0[2 * p + 1]);
    if (DIAG) {
#pragma unroll
      for (int p = 0; p < 2; ++p) srow[8 + quad * 2 + p] = 0;
    } else {
      f32x4 s1 = {};
      s1 = mfma16(k10, qf[0][0], s1);
      s1 = mfma16(k11, qf[0][1], s1);
#pragma unroll
      for (int p = 0; p < 2; ++p) srow[8 + quad * 2 + p] = pack2(s1[2 * p], s1[2 * p + 1]);
    }
  }
  {
    u32* srow = &ssw[1 * 320 + nl * 20];
    f32x4 s0 = {}, s1 = {};
    s0 = mfma16(k00, qf[1][0], s0);
    s0 = mfma16(k01, qf[1][1], s0);
    s1 = mfma16(k10, qf[1][0], s1);
    s1 = mfma16(k11, qf[1][1], s1);
    if (DIAG) {
#pragma unroll
      for (int r = 0; r < 4; ++r) s1[r] = (quad * 4 + r <= nl) ? s1[r] : 0.0f;
    }
#pragma unroll
    for (int p = 0; p < 2; ++p) {
      srow[quad * 2 + p] = pack2(s0[2 * p], s0[2 * p + 1]);
      srow[8 + quad * 2 + p] = pack2(s1[2 * p], s1[2 * p + 1]);
    }
  }
#pragma unroll
  for (int m = 0; m < 2; ++m) {
    bf16x8 sf = *reinterpret_cast<const bf16x8*>(&ssw[m * 320 + nl * 20 + quad * 4]);
#pragma unroll
    for (int nb = 0; nb < 4; ++nb) o[m][nb] = mfma16(sf, vB[nb], o[m][nb]);
  }
}

// ---------------- causal masked attention (no softmax) ------------------------
__global__ __launch_bounds__(256, 3) void attn_kernel(const short* __restrict__ qkv,
                                                      const short* __restrict__ vt,
                                                      short* __restrict__ attnb) {
  const int bh = blockIdx.x;
  const int b = bh >> 4, h = bh & 15;
  const int ti = 15 - blockIdx.y;  // big tiles first
  const int T0 = ti * 128;
  const int tid = threadIdx.x;
  const int wave = tid >> 6, lane = tid & 63;
  const int quad = lane >> 4, nl = lane & 15;

  const short* qbase = qkv + (size_t)(b * TT) * (3 * CC) + h * 64;
  const short* kbase = qbase + CC;
  const short* vbase = vt + (size_t)(bh * 64) * TT;

  __shared__ __align__(16) short Frag[2][8192];  // 2 x 16 KB staged K/V frags
  __shared__ __align__(16) u32 Ss[4][640];       // per-wave S roundtrip (stride 20)
  u32* ssw = Ss[wave];

  const int tw0 = T0 + wave * 32;
  bf16x8 qf[2][2];  // Q B-frags (pre-scaled by 0.125)
#pragma unroll
  for (int m = 0; m < 2; ++m)
#pragma unroll
    for (int half = 0; half < 2; ++half)
      qf[m][half] = *reinterpret_cast<const bf16x8*>(
          &qbase[(size_t)(tw0 + m * 16 + nl) * (3 * CC) + half * 32 + quad * 8]);

  f32x4 o[2][4] = {};

  const short* ksrc = kbase + (size_t)(wave * 16 + nl) * (3 * CC) + quad * 8;
  const int sp_w = wave >> 1, nb0 = (wave & 1) * 2;
  const short* vsrc0 = vbase + (size_t)((nb0 + 0) * 16 + nl) * TT + sp_w * 32 + quad * 8;
  const short* vsrc1 = vbase + (size_t)((nb0 + 1) * 16 + nl) * TT + sp_w * 32 + quad * 8;

  auto stage = [&](short* fb, int c) {
    const size_t koff = (size_t)(c * 64) * (3 * CC);
#if HAVE_GLD_LDS
    gld_lds16(ksrc + koff, &fb[(2 * wave) * 512]);
    gld_lds16(ksrc + koff + 32, &fb[(2 * wave + 1) * 512]);
    gld_lds16(vsrc0 + c * 64, &fb[4096 + (2 * wave) * 512]);
    gld_lds16(vsrc1 + c * 64, &fb[4096 + (2 * wave + 1) * 512]);
#else
    *reinterpret_cast<uint4*>(&fb[(2 * wave) * 512 + lane * 8]) =
        *reinterpret_cast<const uint4*>(ksrc + koff);
    *reinterpret_cast<uint4*>(&fb[(2 * wave + 1) * 512 + lane * 8]) =
        *reinterpret_cast<const uint4*>(ksrc + koff + 32);
    *reinterpret_cast<uint4*>(&fb[4096 + (2 * wave) * 512 + lane * 8]) =
        *reinterpret_cast<const uint4*>(vsrc0 + c * 64);
    *reinterpret_cast<uint4*>(&fb[4096 + (2 * wave + 1) * 512 + lane * 8]) =
        *reinterpret_cast<const uint4*>(vsrc1 + c * 64);
#endif
  };

  const int nch = 2 * ti + 2;     // 64-col chunks
  const int cd = 4 * ti + wave;   // this wave's diagonal 32-chunk index

  stage(Frag[0], 0);
  for (int c = 0; c < nch; ++c) {
    __syncthreads();  // compiler vmcnt(0) here drains stage(c); buf[c&1] ready
    if (c + 1 < nch) stage(Frag[(c + 1) & 1], c + 1);  // overlaps compute below
    const short* fb = Frag[c & 1];
    const int c0 = 2 * c, c1 = 2 * c + 1;
    if (c0 < cd)
      attn_compute<false>(fb, fb + 4096, ssw, qf, o, lane, quad, nl);
    else if (c0 == cd)
      attn_compute<true>(fb, fb + 4096, ssw, qf, o, lane, quad, nl);
    if (c1 < cd)
      attn_compute<false>(fb + 2048, fb + 4096 + 2048, ssw, qf, o, lane, quad, nl);
    else if (c1 == cd)
      attn_compute<true>(fb + 2048, fb + 4096 + 2048, ssw, qf, o, lane, quad, nl);
  }

#pragma unroll
  for (int m = 0; m < 2; ++m)
#pragma unroll
    for (int nb = 0; nb < 4; ++nb)
#pragma unroll
      for (int r = 0; r < 4; ++r) {
        int t = tw0 + m * 16 + quad * 4 + r;
        attnb[(size_t)(b * TT + t) * CC + h * 64 + nb * 16 + nl] = f2bf(o[m][nb][r]);
      }
}

extern "C" void kernel_launch(void* const* d_in, const int* in_sizes, int n_in,
                              void* d_out, int out_size, void* d_ws, size_t ws_size,
                              hipStream_t stream) {
  const float* x = (const float*)d_in[0];      // [4,2048,1024]
  const float* wqkv = (const float*)d_in[1];   // [3072,1024]
  const float* wout = (const float*)d_in[2];   // [1024,1024]
  float* out = (float*)d_out;                  // [4,2048,1024] fp32

  char* ws = (char*)d_ws;
  short* xb    = (short*)(ws);                  // 16.78 MB
  short* wqkvb = (short*)(ws + 16777216);       //  6.29 MB
  short* woutb = (short*)(ws + 23068672);       //  2.10 MB
  short* qkvb  = (short*)(ws + 25165824);       // 50.33 MB
  short* attnb = (short*)(ws + 75497472);       // 16.78 MB  (total 92.27 MB)
  short* vt    = xb;  // xb dead after QKV GEMM

  static bool inited = false;
  if (!inited) {  // dynamic LDS opt-in (not a stream op; capture-safe)
    hipFuncSetAttribute(reinterpret_cast<const void*>(&gemm4p<short, 3072, 1024, 128, 384>),
                        hipFuncAttributeMaxDynamicSharedMemorySize, 131072);
    hipFuncSetAttribute(reinterpret_cast<const void*>(&gemm4p<float, 1024, 1024, 128, 256>),
                        hipFuncAttributeMaxDynamicSharedMemorySize, 98304);
    inited = true;
  }

  cvt_all<<<12288, 256, 0, stream>>>(x, wqkv, wout, xb);

  // QKV: M=8192 N=3072, BM=128 BN=384 -> 64x8 = 512 blocks (2 exact rounds)
  gemm4p<short, 3072, 1024, 128, 384><<<512, 512, 131072, stream>>>(xb, wqkvb, qkvb);

  transpose_v<<<dim3(32, 64), 256, 0, stream>>>(qkvb, vt);

  attn_kernel<<<dim3(64, 16), 256, 0, stream>>>(qkvb, vt, attnb);

  // out-proj: M=8192 N=1024, BM=128 BN=256 -> 64x4 = 256 blocks (1 exact round)
  gemm4p<float, 1024, 1024, 128, 256><<<256, 512, 98304, stream>>>(attnb, woutb, out);
}

// Round 7
// 224.110 us; speedup vs baseline: 1.0630x; 1.0351x over previous
//
#include <hip/hip_runtime.h>

#define TT 2048
#define CC 1024

typedef __attribute__((ext_vector_type(8))) __bf16 bf16x8;
typedef __attribute__((ext_vector_type(4))) float f32x4;
typedef unsigned int u32;

__device__ __forceinline__ short f2bf(float f) {
  u32 u = __float_as_uint(f);
  u += 0x7fffu + ((u >> 16) & 1u);  // RTNE
  return (short)(u >> 16);
}

#if __has_builtin(__builtin_amdgcn_cvt_pk_bf16_f32)
__device__ __forceinline__ u32 pack2(float a, float b) {
  auto v = __builtin_amdgcn_cvt_pk_bf16_f32(a, b);
  return __builtin_bit_cast(u32, v);
}
#else
__device__ __forceinline__ u32 pack2(float a, float b) {
  u32 ua = __float_as_uint(a), ub = __float_as_uint(b);
  ua += 0x7fffu + ((ua >> 16) & 1u);
  ub += 0x7fffu + ((ub >> 16) & 1u);
  return (ua >> 16) | (ub & 0xffff0000u);
}
#endif

// ---------------- fused fp32 -> bf16 cast (x | wqkv(Q scaled) | wout) ---------
__global__ __launch_bounds__(256) void cvt_all(const float* __restrict__ x,
                                               const float* __restrict__ wqkv,
                                               const float* __restrict__ wout,
                                               short* __restrict__ dst) {
  int i = blockIdx.x * blockDim.x + threadIdx.x;  // float4 index, < 3145728
  const float* src;
  float sc = 1.0f;
  if (i < 2097152) {
    src = x + (size_t)i * 4;
  } else if (i < 2883584) {
    int j = i - 2097152;
    src = wqkv + (size_t)j * 4;
    if (j < 262144) sc = 0.125f;  // Q block: fold attention scale (exact pow2)
  } else {
    src = wout + (size_t)(i - 2883584) * 4;
  }
  float4 f = *reinterpret_cast<const float4*>(src);
  short4 s;
  s.x = f2bf(f.x * sc); s.y = f2bf(f.y * sc); s.z = f2bf(f.z * sc); s.w = f2bf(f.w * sc);
  reinterpret_cast<short4*>(dst)[i] = s;
}

__device__ __forceinline__ void storev(float* p, float v) { *p = v; }
__device__ __forceinline__ void storev(short* p, float v) { *p = f2bf(v); }

#if __has_builtin(__builtin_amdgcn_global_load_lds)
#define HAVE_GLD_LDS 1
__device__ __forceinline__ void gld_lds16(const short* g, short* l) {
  __builtin_amdgcn_global_load_lds((const __attribute__((address_space(1))) u32*)g,
                                   (__attribute__((address_space(3))) u32*)l, 16, 0, 0);
}
#endif

__device__ __forceinline__ f32x4 mfma16(bf16x8 a, bf16x8 b, f32x4 c) {
  return __builtin_amdgcn_mfma_f32_16x16x32_bf16(a, b, c, 0, 0, 0);
}

template <int NN>
__device__ __forceinline__ void waitvm() {
  if constexpr (NN == 0) asm volatile("s_waitcnt vmcnt(0)" ::: "memory");
  else if constexpr (NN == 3) asm volatile("s_waitcnt vmcnt(3)" ::: "memory");
  else if constexpr (NN == 4) asm volatile("s_waitcnt vmcnt(4)" ::: "memory");
  else if constexpr (NN == 6) asm volatile("s_waitcnt vmcnt(6)" ::: "memory");
  else if constexpr (NN == 8) asm volatile("s_waitcnt vmcnt(8)" ::: "memory");
}

// =================== C[M,N] = A[M,K] * B[N,K]^T, 128xBN 4-phase ===============
// (unchanged from round 4 — see comments there)
#define GNOOP ((void)0)
#define GPHASE4(DB, KS, STG, SYNC)                         \
  {                                                        \
    bf16x8 af[MFRAG], bfr[NFR];                            \
    ldA(af, DB, KS);                                       \
    ldB(bfr, DB, KS);                                      \
    STG;                                                   \
    __builtin_amdgcn_s_setprio(1);                         \
    mmaAll(af, bfr);                                       \
    __builtin_amdgcn_s_setprio(0);                         \
    asm volatile("s_waitcnt lgkmcnt(0)" ::: "memory");     \
    SYNC;                                                  \
    __builtin_amdgcn_s_barrier();                          \
  }

template <typename OutT, int N, int K, int BM, int BN>
__global__ __launch_bounds__(512, 2) void gemm4p(const short* __restrict__ A,
                                                 const short* __restrict__ B,
                                                 OutT* __restrict__ Cm) {
  constexpr int MFRAG = BM / 32;
  constexpr int NFR = BN / 64;
  constexpr int AGLD = BM / 128;
  constexpr int BGLD = BN / 128;
  constexpr int GPP = AGLD + BGLD;
  constexpr int SYNCN = 2 * GPP;
  constexpr int NT = K / 64, NITER = NT / 2;
  constexpr int DBS = 64 * (BM + BN);
  constexpr int TMX = (8192 / BM) / 8;
  extern __shared__ short lds[];
  const int tid = threadIdx.x;
  const int wave = tid >> 6, lane = tid & 63;
  const int quad = lane >> 4, nl = lane & 15;
  const int wm = wave >> 2, wn = wave & 3;

  const int id = blockIdx.x;
  const int xcd = id & 7, slot = id >> 3;
  const int mt = xcd * TMX + (slot % TMX);
  const int nt = slot / TMX;
  const int m0 = mt * BM, n0 = nt * BN;

  const int srow = lane >> 2;
  const int sperm = ((lane & 3) ^ ((lane >> 3) & 3)) * 8;
  const short* pA = A + (size_t)(m0 + wave * (BM / 8) + srow) * K + sperm;
  const short* pB = B + (size_t)(n0 + wave * (BN / 8) + srow) * K + sperm;

  const int perm = (quad ^ ((nl >> 1) & 3)) * 8;

  f32x4 acc[MFRAG][NFR] = {};

  auto stageA = [&](int db, int ks, int t) {
    const short* s = pA + (size_t)t * 64 + ks * 32;
    short* d = lds + db * DBS + ks * (BM * 32) + wave * (BM * 4);
#pragma unroll
    for (int j = 0; j < AGLD; ++j) {
#if HAVE_GLD_LDS
      gld_lds16(s + (size_t)j * 16 * K, d + j * 512);
#else
      *reinterpret_cast<uint4*>(d + j * 512 + lane * 8) =
          *reinterpret_cast<const uint4*>(s + (size_t)j * 16 * K);
#endif
    }
  };
  auto stageB = [&](int db, int ks, int t) {
    const short* s = pB + (size_t)t * 64 + ks * 32;
    short* d = lds + db * DBS + BM * 64 + ks * (BN * 32) + wave * (BN * 4);
#pragma unroll
    for (int j = 0; j < BGLD; ++j) {
#if HAVE_GLD_LDS
      gld_lds16(s + (size_t)j * 16 * K, d + j * 512);
#else
      *reinterpret_cast<uint4*>(d + j * 512 + lane * 8) =
          *reinterpret_cast<const uint4*>(s + (size_t)j * 16 * K);
#endif
    }
  };
  auto stage = [&](int db, int ks, int t) { stageA(db, ks, t); stageB(db, ks, t); };

  auto ldA = [&](bf16x8 (&af)[MFRAG], int db, int ks) {
#pragma unroll
    for (int mf = 0; mf < MFRAG; ++mf)
      af[mf] = *reinterpret_cast<const bf16x8*>(
          &lds[db * DBS + ks * (BM * 32) + (wm * (BM / 2) + mf * 16 + nl) * 32 + perm]);
  };
  auto ldB = [&](bf16x8 (&bfr)[NFR], int db, int ks) {
#pragma unroll
    for (int nf = 0; nf < NFR; ++nf)
      bfr[nf] = *reinterpret_cast<const bf16x8*>(
          &lds[db * DBS + BM * 64 + ks * (BN * 32) + (wn * (BN / 4) + nf * 16 + nl) * 32 + perm]);
  };
  auto mmaAll = [&](const bf16x8 (&af)[MFRAG], const bf16x8 (&bfr)[NFR]) {
#pragma unroll
    for (int mf = 0; mf < MFRAG; ++mf)
#pragma unroll
      for (int nf = 0; nf < NFR; ++nf)
        acc[mf][nf] = mfma16(af[mf], bfr[nf], acc[mf][nf]);
  };

  stage(0, 0, 0); stage(0, 1, 0); stage(1, 0, 1);
  waitvm<SYNCN>();
  __builtin_amdgcn_s_barrier();

  for (int i = 0; i < NITER - 1; ++i) {
    GPHASE4(0, 0, stage(1, 1, 2 * i + 1), waitvm<SYNCN>())
    GPHASE4(0, 1, stage(0, 0, 2 * i + 2), waitvm<SYNCN>())
    GPHASE4(1, 0, stage(0, 1, 2 * i + 2), waitvm<SYNCN>())
    GPHASE4(1, 1, stage(1, 0, 2 * i + 3), waitvm<SYNCN>())
  }
  GPHASE4(0, 0, stage(1, 1, NT - 1), waitvm<SYNCN>())
  GPHASE4(0, 1, GNOOP, waitvm<GPP>())
  GPHASE4(1, 0, GNOOP, waitvm<0>())
  GPHASE4(1, 1, GNOOP, GNOOP)

#pragma unroll
  for (int mf = 0; mf < MFRAG; ++mf) {
    const int row = m0 + wm * (BM / 2) + mf * 16 + quad * 4;
#pragma unroll
    for (int nf = 0; nf < NFR; ++nf) {
      const int col = n0 + wn * (BN / 4) + nf * 16 + nl;
#pragma unroll
      for (int r = 0; r < 4; ++r)
        storev(&Cm[(size_t)(row + r) * N + col], acc[mf][nf][r]);
    }
  }
}

// ---------------- V transpose: qkv V-part -> Vt[bh][d][t] ---------------------
__global__ __launch_bounds__(256) void transpose_v(const short* __restrict__ qkv,
                                                   short* __restrict__ vt) {
  __shared__ short Ls[64 * 68];
  const int bh = blockIdx.y, tb = blockIdx.x;
  const int b = bh >> 4, h = bh & 15;
  const int tid = threadIdx.x;
  const short* src = qkv + (size_t)(b * TT + tb * 64) * (3 * CC) + 2 * CC + h * 64;
#pragma unroll
  for (int i = 0; i < 2; ++i) {
    int idx = tid + i * 256;
    int tl = idx >> 3, dc = idx & 7;
    uint4 d4 = *reinterpret_cast<const uint4*>(&src[(size_t)tl * (3 * CC) + dc * 8]);
    *reinterpret_cast<uint2*>(&Ls[tl * 68 + dc * 8]) = make_uint2(d4.x, d4.y);
    *reinterpret_cast<uint2*>(&Ls[tl * 68 + dc * 8 + 4]) = make_uint2(d4.z, d4.w);
  }
  __syncthreads();
  short* dst = vt + (size_t)(bh * 64) * TT + tb * 64;
#pragma unroll
  for (int i = 0; i < 2; ++i) {
    int idx = tid + i * 256;
    int dl = idx >> 3, tc = idx & 7;
    short tmp[8];
#pragma unroll
    for (int j = 0; j < 8; ++j) tmp[j] = Ls[(tc * 8 + j) * 68 + dl];
    *reinterpret_cast<uint4*>(&dst[(size_t)dl * TT + tc * 8]) = *reinterpret_cast<uint4*>(tmp);
  }
}

// ---------------- attention compute (one 32-col half-chunk, one wave) ---------
// (round-4 verified version: S roundtrip through per-wave LDS buffer)
template <bool DIAG>
__device__ __forceinline__ void attn_compute(const short* kf, const short* vf, u32* ssw,
                                             const bf16x8 (&qf)[2][2], f32x4 (&o)[2][4],
                                             int lane, int quad, int nl) {
  bf16x8 k00 = *reinterpret_cast<const bf16x8*>(&kf[0 * 512 + lane * 8]);
  bf16x8 k01 = *reinterpret_cast<const bf16x8*>(&kf[1 * 512 + lane * 8]);
  bf16x8 k10 = *reinterpret_cast<const bf16x8*>(&kf[2 * 512 + lane * 8]);
  bf16x8 k11 = *reinterpret_cast<const bf16x8*>(&kf[3 * 512 + lane * 8]);
  bf16x8 vB[4];
#pragma unroll
  for (int nb = 0; nb < 4; ++nb)
    vB[nb] = *reinterpret_cast<const bf16x8*>(&vf[nb * 512 + lane * 8]);
  {
    u32* srow = &ssw[0 * 320 + nl * 20];
    f32x4 s0 = {};
    s0 = mfma16(k00, qf[0][0], s0);
    s0 = mfma16(k01, qf[0][1], s0);
    if (DIAG) {
#pragma unroll
      for (int r = 0; r < 4; ++r) s0[r] = (quad * 4 + r <= nl) ? s0[r] : 0.0f;
    }
#pragma unroll
    for (int p = 0; p < 2; ++p) srow[quad * 2 + p] = pack2(s0[2 * p], s0[2 * p + 1]);
    if (DIAG) {
#pragma unroll
      for (int p = 0; p < 2; ++p) srow[8 + quad * 2 + p] = 0;
    } else {
      f32x4 s1 = {};
      s1 = mfma16(k10, qf[0][0], s1);
      s1 = mfma16(k11, qf[0][1], s1);
#pragma unroll
      for (int p = 0; p < 2; ++p) srow[8 + quad * 2 + p] = pack2(s1[2 * p], s1[2 * p + 1]);
    }
  }
  {
    u32* srow = &ssw[1 * 320 + nl * 20];
    f32x4 s0 = {}, s1 = {};
    s0 = mfma16(k00, qf[1][0], s0);
    s0 = mfma16(k01, qf[1][1], s0);
    s1 = mfma16(k10, qf[1][0], s1);
    s1 = mfma16(k11, qf[1][1], s1);
    if (DIAG) {
#pragma unroll
      for (int r = 0; r < 4; ++r) s1[r] = (quad * 4 + r <= nl) ? s1[r] : 0.0f;
    }
#pragma unroll
    for (int p = 0; p < 2; ++p) {
      srow[quad * 2 + p] = pack2(s0[2 * p], s0[2 * p + 1]);
      srow[8 + quad * 2 + p] = pack2(s1[2 * p], s1[2 * p + 1]);
    }
  }
#pragma unroll
  for (int m = 0; m < 2; ++m) {
    bf16x8 sf = *reinterpret_cast<const bf16x8*>(&ssw[m * 320 + nl * 20 + quad * 4]);
#pragma unroll
    for (int nb = 0; nb < 4; ++nb) o[m][nb] = mfma16(sf, vB[nb], o[m][nb]);
  }
}

// ---------------- causal masked attention (no softmax) ------------------------
// 1D grid, XCD-chunked: xcd = gid&7 owns bh in [xcd*8, xcd*8+8) x all 16 tiles
// -> each bh's 512 KB K/V is L2-resident and read 16x from the same XCD
// (8 bh x 512 KB = 4 MB = one XCD's L2). Tile order still descending
// (big tiles dispatched first for load balance).
__global__ __launch_bounds__(256, 3) void attn_kernel(const short* __restrict__ qkv,
                                                      const short* __restrict__ vt,
                                                      short* __restrict__ attnb) {
  const int gid = blockIdx.x;
  const int xcd = gid & 7, slot = gid >> 3;
  const int bh = xcd * 8 + (slot & 7);
  const int ti = 15 - (slot >> 3);  // big tiles first
  const int b = bh >> 4, h = bh & 15;
  const int T0 = ti * 128;
  const int tid = threadIdx.x;
  const int wave = tid >> 6, lane = tid & 63;
  const int quad = lane >> 4, nl = lane & 15;

  const short* qbase = qkv + (size_t)(b * TT) * (3 * CC) + h * 64;
  const short* kbase = qbase + CC;
  const short* vbase = vt + (size_t)(bh * 64) * TT;

  __shared__ __align__(16) short Frag[2][8192];  // 2 x 16 KB staged K/V frags
  __shared__ __align__(16) u32 Ss[4][640];       // per-wave S roundtrip (stride 20)
  u32* ssw = Ss[wave];

  const int tw0 = T0 + wave * 32;
  bf16x8 qf[2][2];  // Q B-frags (pre-scaled by 0.125)
#pragma unroll
  for (int m = 0; m < 2; ++m)
#pragma unroll
    for (int half = 0; half < 2; ++half)
      qf[m][half] = *reinterpret_cast<const bf16x8*>(
          &qbase[(size_t)(tw0 + m * 16 + nl) * (3 * CC) + half * 32 + quad * 8]);

  f32x4 o[2][4] = {};

  const short* ksrc = kbase + (size_t)(wave * 16 + nl) * (3 * CC) + quad * 8;
  const int sp_w = wave >> 1, nb0 = (wave & 1) * 2;
  const short* vsrc0 = vbase + (size_t)((nb0 + 0) * 16 + nl) * TT + sp_w * 32 + quad * 8;
  const short* vsrc1 = vbase + (size_t)((nb0 + 1) * 16 + nl) * TT + sp_w * 32 + quad * 8;

  auto stage = [&](short* fb, int c) {
    const size_t koff = (size_t)(c * 64) * (3 * CC);
#if HAVE_GLD_LDS
    gld_lds16(ksrc + koff, &fb[(2 * wave) * 512]);
    gld_lds16(ksrc + koff + 32, &fb[(2 * wave + 1) * 512]);
    gld_lds16(vsrc0 + c * 64, &fb[4096 + (2 * wave) * 512]);
    gld_lds16(vsrc1 + c * 64, &fb[4096 + (2 * wave + 1) * 512]);
#else
    *reinterpret_cast<uint4*>(&fb[(2 * wave) * 512 + lane * 8]) =
        *reinterpret_cast<const uint4*>(ksrc + koff);
    *reinterpret_cast<uint4*>(&fb[(2 * wave + 1) * 512 + lane * 8]) =
        *reinterpret_cast<const uint4*>(ksrc + koff + 32);
    *reinterpret_cast<uint4*>(&fb[4096 + (2 * wave) * 512 + lane * 8]) =
        *reinterpret_cast<const uint4*>(vsrc0 + c * 64);
    *reinterpret_cast<uint4*>(&fb[4096 + (2 * wave + 1) * 512 + lane * 8]) =
        *reinterpret_cast<const uint4*>(vsrc1 + c * 64);
#endif
  };

  const int nch = 2 * ti + 2;     // 64-col chunks
  const int cd = 4 * ti + wave;   // this wave's diagonal 32-chunk index

  stage(Frag[0], 0);
  for (int c = 0; c < nch; ++c) {
    __syncthreads();  // compiler vmcnt(0) here drains stage(c); buf[c&1] ready
    if (c + 1 < nch) stage(Frag[(c + 1) & 1], c + 1);  // overlaps compute below
    const short* fb = Frag[c & 1];
    const int c0 = 2 * c, c1 = 2 * c + 1;
    if (c0 < cd)
      attn_compute<false>(fb, fb + 4096, ssw, qf, o, lane, quad, nl);
    else if (c0 == cd)
      attn_compute<true>(fb, fb + 4096, ssw, qf, o, lane, quad, nl);
    if (c1 < cd)
      attn_compute<false>(fb + 2048, fb + 4096 + 2048, ssw, qf, o, lane, quad, nl);
    else if (c1 == cd)
      attn_compute<true>(fb + 2048, fb + 4096 + 2048, ssw, qf, o, lane, quad, nl);
  }

  // epilogue: O C-layout row=t(quad*4+r), col=d(nl) -> attnb[b][t][h*64+d]
#pragma unroll
  for (int m = 0; m < 2; ++m)
#pragma unroll
    for (int nb = 0; nb < 4; ++nb)
#pragma unroll
      for (int r = 0; r < 4; ++r) {
        int t = tw0 + m * 16 + quad * 4 + r;
        attnb[(size_t)(b * TT + t) * CC + h * 64 + nb * 16 + nl] = f2bf(o[m][nb][r]);
      }
}

extern "C" void kernel_launch(void* const* d_in, const int* in_sizes, int n_in,
                              void* d_out, int out_size, void* d_ws, size_t ws_size,
                              hipStream_t stream) {
  const float* x = (const float*)d_in[0];      // [4,2048,1024]
  const float* wqkv = (const float*)d_in[1];   // [3072,1024]
  const float* wout = (const float*)d_in[2];   // [1024,1024]
  float* out = (float*)d_out;                  // [4,2048,1024] fp32

  char* ws = (char*)d_ws;
  short* xb    = (short*)(ws);                  // 16.78 MB
  short* wqkvb = (short*)(ws + 16777216);       //  6.29 MB
  short* woutb = (short*)(ws + 23068672);       //  2.10 MB
  short* qkvb  = (short*)(ws + 25165824);       // 50.33 MB
  short* attnb = (short*)(ws + 75497472);       // 16.78 MB  (total 92.27 MB)
  short* vt    = xb;  // xb dead after QKV GEMM

  static bool inited = false;
  if (!inited) {  // dynamic LDS opt-in (not a stream op; capture-safe)
    (void)hipFuncSetAttribute(reinterpret_cast<const void*>(&gemm4p<short, 3072, 1024, 128, 384>),
                              hipFuncAttributeMaxDynamicSharedMemorySize, 131072);
    (void)hipFuncSetAttribute(reinterpret_cast<const void*>(&gemm4p<float, 1024, 1024, 128, 256>),
                              hipFuncAttributeMaxDynamicSharedMemorySize, 98304);
    inited = true;
  }

  cvt_all<<<12288, 256, 0, stream>>>(x, wqkv, wout, xb);

  // QKV: M=8192 N=3072, BM=128 BN=384 -> 64x8 = 512 blocks (2 exact rounds)
  gemm4p<short, 3072, 1024, 128, 384><<<512, 512, 131072, stream>>>(xb, wqkvb, qkvb);

  transpose_v<<<dim3(32, 64), 256, 0, stream>>>(qkvb, vt);

  attn_kernel<<<1024, 256, 0, stream>>>(qkvb, vt, attnb);

  // out-proj: M=8192 N=1024, BM=128 BN=256 -> 64x4 = 256 blocks (1 exact round)
  gemm4p<float, 1024, 1024, 128, 256><<<256, 512, 98304, stream>>>(attnb, woutb, out);
}